// Round 1
// baseline (428.193 us; speedup 1.0000x reference)
//
#include <hip/hip_runtime.h>
#include <hip/hip_bf16.h>

// SiLU forward: out = x * sigmoid(x) = x / (1 + exp(-x))
// x: (4, 4096, 4096) fp32 = 67,108,864 elements. Memory-bound elementwise.
// float4 vectorized, grid-stride loop, 2048 blocks x 256 threads.

__device__ __forceinline__ float silu(float x) {
    // x * sigmoid(x) = x / (1 + exp(-x))
    return x / (1.0f + __expf(-x));
}

__global__ void __launch_bounds__(256)
silu_fwd_kernel(const float* __restrict__ in, float* __restrict__ out, long long n4) {
    // n4 = number of float4 elements
    const float4* __restrict__ in4 = (const float4*)in;
    float4* __restrict__ out4 = (float4*)out;

    long long stride = (long long)gridDim.x * blockDim.x;
    for (long long i = (long long)blockIdx.x * blockDim.x + threadIdx.x; i < n4; i += stride) {
        float4 v = in4[i];
        float4 r;
        r.x = silu(v.x);
        r.y = silu(v.y);
        r.z = silu(v.z);
        r.w = silu(v.w);
        out4[i] = r;
    }
}

__global__ void silu_fwd_tail_kernel(const float* __restrict__ in, float* __restrict__ out,
                                     long long start, long long n) {
    long long i = start + blockIdx.x * blockDim.x + threadIdx.x;
    if (i < n) out[i] = silu(in[i]);
}

extern "C" void kernel_launch(void* const* d_in, const int* in_sizes, int n_in,
                              void* d_out, int out_size, void* d_ws, size_t ws_size,
                              hipStream_t stream) {
    const float* x = (const float*)d_in[0];
    float* out = (float*)d_out;
    long long n = (long long)in_sizes[0];  // 67,108,864

    long long n4 = n / 4;
    const int block = 256;
    // Memory-bound: cap grid at ~2048 blocks (256 CU x 8), grid-stride the rest.
    long long want = (n4 + block - 1) / block;
    int grid = (int)(want < 2048 ? want : 2048);
    if (grid < 1) grid = 1;

    silu_fwd_kernel<<<grid, block, 0, stream>>>(x, out, n4);

    long long rem = n - n4 * 4;
    if (rem > 0) {
        int tgrid = (int)((rem + block - 1) / block);
        silu_fwd_tail_kernel<<<tgrid, block, 0, stream>>>(x, out, n4 * 4, n);
    }
}